// Round 1
// baseline (438.715 us; speedup 1.0000x reference)
//
#include <hip/hip_runtime.h>
#include <hip/hip_fp16.h>

// RelativeMultiHeadAttention on MI355X (gfx950), fp16 MFMA pipeline.
//
// Stages:
//  K0  cvt:     wo, rel_emb fp32 -> fp16 in ws
//  K1  qkv_proj: q/k/v @ W^T + b -> qh[B,H,L,dk], kh[B,H,L,dk], vt[B,H,dk,L] (fp16)
//  K2  flash_attn: per (b,h, 64-row Q tile): iterate 64-col K tiles,
//       content = Q K^T (MFMA), pos = skew(Q @ relband^T) (MFMA + LDS gather),
//       online softmax (fp32), PV accumulate (MFMA) -> att[B*L, D] fp16
//  K3  out_proj: att @ wo^T + bo -> d_out fp32
//
// MFMA 16x16x32_f16 fragment convention (m97-verified):
//   A/B operand: row/col = lane&15, k = 8*(lane>>4)+j (8 contiguous halves -> ds_read_b128)
//   C/D:         col = lane&15,     row = 4*(lane>>4)+reg

typedef _Float16 f16;
typedef _Float16 f16x4 __attribute__((ext_vector_type(4)));
typedef _Float16 f16x8 __attribute__((ext_vector_type(8)));
typedef float    f32x4 __attribute__((ext_vector_type(4)));

#define NBATCH 2
#define NHEADS 16
#define DKDIM  64
#define SEQL   2048
#define DMODEL 1024
#define NTOK   4096   // NBATCH*SEQL
#define MAXLEN 2048

// ---------------------------------------------------------------- K0: convert
__global__ void cvt_f32_f16(const float* __restrict__ src, f16* __restrict__ dst, int n4) {
    int i = blockIdx.x * blockDim.x + threadIdx.x;
    if (i < n4) {
        float4 v = ((const float4*)src)[i];
        f16x4 h = { (f16)v.x, (f16)v.y, (f16)v.z, (f16)v.w };
        ((f16x4*)dst)[i] = h;
    }
}

// ------------------------------------------------------------ K1: QKV project
// C[n,o] = sum_i X[n,i]*W[o,i] + b[o]; 128x128 tile, 4 waves (2x2), BK=32.
__global__ __launch_bounds__(256) void qkv_proj(
    const float* __restrict__ qg, const float* __restrict__ kg, const float* __restrict__ vg,
    const float* __restrict__ wq, const float* __restrict__ wk, const float* __restrict__ wv,
    const float* __restrict__ bq, const float* __restrict__ bk, const float* __restrict__ bv,
    f16* __restrict__ qh, f16* __restrict__ kh, f16* __restrict__ vt)
{
    const int which = blockIdx.z;
    const float* X    = which == 0 ? qg : (which == 1 ? kg : vg);
    const float* W    = which == 0 ? wq : (which == 1 ? wk : wv);
    const float* bias = which == 0 ? bq : (which == 1 ? bk : bv);

    __shared__ f16 As[128][40];   // +8 pad: stride 80B (16B-aligned, conflict-light)
    __shared__ f16 Bs[128][40];

    const int tid = threadIdx.x;
    const int lane = tid & 63;
    const int w = tid >> 6;
    const int wr = w >> 1, wc = w & 1;
    const int row0 = blockIdx.y * 128;
    const int col0 = blockIdx.x * 128;

    f32x4 acc[4][4] = {};

    for (int kk = 0; kk < DMODEL; kk += 32) {
        // stage + convert: 128x32 fp32 of X and W
        #pragma unroll
        for (int rep = 0; rep < 4; ++rep) {
            int idx = rep * 256 + tid;        // 0..1023
            int r = idx >> 3, seg = idx & 7;  // row, 4-float segment
            float4 va = *(const float4*)&X[(size_t)(row0 + r) * DMODEL + kk + seg * 4];
            f16x4 ha = { (f16)va.x, (f16)va.y, (f16)va.z, (f16)va.w };
            *(f16x4*)&As[r][seg * 4] = ha;
            float4 vb = *(const float4*)&W[(size_t)(col0 + r) * DMODEL + kk + seg * 4];
            f16x4 hb = { (f16)vb.x, (f16)vb.y, (f16)vb.z, (f16)vb.w };
            *(f16x4*)&Bs[r][seg * 4] = hb;
        }
        __syncthreads();

        f16x8 a[4], b[4];
        #pragma unroll
        for (int mi = 0; mi < 4; ++mi)
            a[mi] = *(const f16x8*)&As[wr * 64 + mi * 16 + (lane & 15)][(lane >> 4) * 8];
        #pragma unroll
        for (int ni = 0; ni < 4; ++ni)
            b[ni] = *(const f16x8*)&Bs[wc * 64 + ni * 16 + (lane & 15)][(lane >> 4) * 8];
        #pragma unroll
        for (int mi = 0; mi < 4; ++mi)
            #pragma unroll
            for (int ni = 0; ni < 4; ++ni)
                acc[mi][ni] = __builtin_amdgcn_mfma_f32_16x16x32_f16(a[mi], b[ni], acc[mi][ni], 0, 0, 0);
        __syncthreads();
    }

    // epilogue: +bias, scatter into head layouts
    #pragma unroll
    for (int mi = 0; mi < 4; ++mi) {
        #pragma unroll
        for (int ni = 0; ni < 4; ++ni) {
            int col = col0 + wc * 64 + ni * 16 + (lane & 15);
            int h = col >> 6, d = col & 63;
            float bc = bias[col];
            #pragma unroll
            for (int r = 0; r < 4; ++r) {
                int row = row0 + wr * 64 + mi * 16 + (lane >> 4) * 4 + r;
                int b_ = row >> 11, l = row & 2047;
                float val = acc[mi][ni][r] + bc;
                if (which == 0)
                    qh[((size_t)((b_ * 16 + h) * 2048 + l)) * 64 + d] = (f16)val;
                else if (which == 1)
                    kh[((size_t)((b_ * 16 + h) * 2048 + l)) * 64 + d] = (f16)val;
                else
                    vt[((size_t)((b_ * 16 + h) * 64 + d)) * 2048 + l] = (f16)val;
            }
        }
    }
}

// --------------------------------------------------------- K2: flash attention
// Block: 256 thr (4 waves), Q tile = 64 rows (wave w owns rows [16w,16w+16)),
// K/V tiles = 64. pos_score via Qr = Q @ relband^T (band = 128 rows), skew gather.
__global__ __launch_bounds__(256) void flash_attn(
    const f16* __restrict__ qh, const f16* __restrict__ kh, const f16* __restrict__ vt,
    const f16* __restrict__ rel, f16* __restrict__ att)
{
    const int tid = threadIdx.x, lane = tid & 63, w = tid >> 6;
    const int bh = blockIdx.y;          // b*16 + h
    const int b = bh >> 4, h = bh & 15;
    const int i0 = blockIdx.x * 64;

    __shared__ f16 Ks[64][72];
    __shared__ f16 Vs[64][72];          // Vs[d][j]
    __shared__ f16 Rb[128][72];         // rel band rows
    __shared__ f16 Qr[64][128];         // Q stage, then Qr=Q@Rb^T (skew source)
    __shared__ f16 Ps[4][16][72];       // per-wave P tile (A-operand relayout)

    const size_t base_kq = (size_t)bh * SEQL * DKDIM;

    // stage Q (64x64) into Qr buffer
    #pragma unroll
    for (int rep = 0; rep < 2; ++rep) {
        int idx = rep * 256 + tid;       // 0..511
        int r = idx >> 3, c8 = idx & 7;
        *(int4*)&Qr[r][c8 * 8] = *(const int4*)&qh[base_kq + (size_t)(i0 + r) * 64 + c8 * 8];
    }
    __syncthreads();
    f16x8 aq[2];
    aq[0] = *(const f16x8*)&Qr[w * 16 + (lane & 15)][(lane >> 4) * 8];
    aq[1] = *(const f16x8*)&Qr[w * 16 + (lane & 15)][32 + (lane >> 4) * 8];
    __syncthreads();   // everyone has Q frags before Qr is reused

    float mrun[4], lrun[4];
    f32x4 oacc[4] = {};
    #pragma unroll
    for (int r = 0; r < 4; ++r) { mrun[r] = -1e30f; lrun[r] = 0.f; }

    for (int j0 = 0; j0 < SEQL; j0 += 64) {
        // ---- stage K tile, V tile (transposed layout), rel band
        #pragma unroll
        for (int rep = 0; rep < 2; ++rep) {
            int idx = rep * 256 + tid;
            int r = idx >> 3, c8 = idx & 7;
            *(int4*)&Ks[r][c8 * 8] = *(const int4*)&kh[base_kq + (size_t)(j0 + r) * 64 + c8 * 8];
            *(int4*)&Vs[r][c8 * 8] = *(const int4*)&vt[base_kq + (size_t)r * 2048 + j0 + c8 * 8];
        }
        const int p0 = j0 - i0 - 63 + MAXLEN;   // >= 1 always
        #pragma unroll
        for (int rep = 0; rep < 4; ++rep) {
            int idx = rep * 256 + tid;          // 0..1023
            int r = idx >> 3, c8 = idx & 7;
            int p = p0 + r; if (p > 4095) p = 4095;   // row 127 unused when clamped
            *(int4*)&Rb[r][c8 * 8] = *(const int4*)&rel[(size_t)p * 64 + c8 * 8];
        }
        __syncthreads();

        // ---- content scores S (16 own rows x 64 cols)
        f32x4 sacc[4] = {};
        #pragma unroll
        for (int nf = 0; nf < 4; ++nf)
            #pragma unroll
            for (int ks = 0; ks < 2; ++ks) {
                f16x8 bk = *(const f16x8*)&Ks[nf * 16 + (lane & 15)][ks * 32 + (lane >> 4) * 8];
                sacc[nf] = __builtin_amdgcn_mfma_f32_16x16x32_f16(aq[ks], bk, sacc[nf], 0, 0, 0);
            }
        // ---- Qr = Q @ band^T (16 own rows x 128 band cols)
        f32x4 qracc[8] = {};
        #pragma unroll
        for (int pf = 0; pf < 8; ++pf)
            #pragma unroll
            for (int ks = 0; ks < 2; ++ks) {
                f16x8 br = *(const f16x8*)&Rb[pf * 16 + (lane & 15)][ks * 32 + (lane >> 4) * 8];
                qracc[pf] = __builtin_amdgcn_mfma_f32_16x16x32_f16(aq[ks], br, qracc[pf], 0, 0, 0);
            }
        // write Qr to LDS (each wave its own 16 rows)
        #pragma unroll
        for (int pf = 0; pf < 8; ++pf)
            #pragma unroll
            for (int r = 0; r < 4; ++r)
                Qr[w * 16 + (lane >> 4) * 4 + r][pf * 16 + (lane & 15)] = (f16)qracc[pf][r];
        __syncthreads();

        // ---- skew gather + scale, then online softmax (rows live in 16-lane groups)
        float p_[4][4];                       // [nf][reg]
        #pragma unroll
        for (int nf = 0; nf < 4; ++nf)
            #pragma unroll
            for (int r = 0; r < 4; ++r) {
                int gi = w * 16 + (lane >> 4) * 4 + r;   // tile-local row
                int jl = nf * 16 + (lane & 15);          // tile-local col
                p_[nf][r] = (sacc[nf][r] + (float)Qr[gi][jl - gi + 63]) * 0.125f;
            }
        float scale[4];
        #pragma unroll
        for (int r = 0; r < 4; ++r) {
            float mx = fmaxf(fmaxf(p_[0][r], p_[1][r]), fmaxf(p_[2][r], p_[3][r]));
            #pragma unroll
            for (int m = 8; m >= 1; m >>= 1) mx = fmaxf(mx, __shfl_xor(mx, m, 64));
            float mnew = fmaxf(mrun[r], mx);
            scale[r] = __expf(mrun[r] - mnew);
            float sm = 0.f;
            #pragma unroll
            for (int nf = 0; nf < 4; ++nf) { p_[nf][r] = __expf(p_[nf][r] - mnew); sm += p_[nf][r]; }
            #pragma unroll
            for (int m = 8; m >= 1; m >>= 1) sm += __shfl_xor(sm, m, 64);
            lrun[r] = lrun[r] * scale[r] + sm;
            mrun[r] = mnew;
        }
        #pragma unroll
        for (int df = 0; df < 4; ++df)
            #pragma unroll
            for (int r = 0; r < 4; ++r) oacc[df][r] *= scale[r];

        // ---- P -> LDS (relayout to A-operand), PV accumulate
        #pragma unroll
        for (int nf = 0; nf < 4; ++nf)
            #pragma unroll
            for (int r = 0; r < 4; ++r)
                Ps[w][(lane >> 4) * 4 + r][nf * 16 + (lane & 15)] = (f16)p_[nf][r];
        __syncthreads();
        f16x8 pa[2];
        pa[0] = *(const f16x8*)&Ps[w][lane & 15][(lane >> 4) * 8];
        pa[1] = *(const f16x8*)&Ps[w][lane & 15][32 + (lane >> 4) * 8];
        #pragma unroll
        for (int df = 0; df < 4; ++df)
            #pragma unroll
            for (int ks = 0; ks < 2; ++ks) {
                f16x8 bv = *(const f16x8*)&Vs[df * 16 + (lane & 15)][ks * 32 + (lane >> 4) * 8];
                oacc[df] = __builtin_amdgcn_mfma_f32_16x16x32_f16(pa[ks], bv, oacc[df], 0, 0, 0);
            }
        __syncthreads();   // before next tile's staging overwrites Ks/Vs/Rb
    }

    // ---- epilogue: normalize, write att[b*L + i][h*64 + d]
    #pragma unroll
    for (int df = 0; df < 4; ++df) {
        int d = df * 16 + (lane & 15);
        #pragma unroll
        for (int r = 0; r < 4; ++r) {
            int i = i0 + w * 16 + (lane >> 4) * 4 + r;
            float val = oacc[df][r] / lrun[r];
            att[((size_t)(b * 2048 + i)) * DMODEL + h * 64 + d] = (f16)val;
        }
    }
}

// ------------------------------------------------------------- K3: out project
__global__ __launch_bounds__(256) void out_proj(
    const f16* __restrict__ att, const f16* __restrict__ wo16, const float* __restrict__ bo,
    float* __restrict__ out)
{
    __shared__ f16 As[128][40];
    __shared__ f16 Bs[128][40];
    const int tid = threadIdx.x, lane = tid & 63, w = tid >> 6;
    const int wr = w >> 1, wc = w & 1;
    const int row0 = blockIdx.y * 128, col0 = blockIdx.x * 128;

    f32x4 acc[4][4] = {};

    for (int kk = 0; kk < DMODEL; kk += 32) {
        #pragma unroll
        for (int rep = 0; rep < 2; ++rep) {
            int idx = rep * 256 + tid;       // 0..511
            int r = idx >> 2, c8 = idx & 3;
            *(int4*)&As[r][c8 * 8] = *(const int4*)&att[(size_t)(row0 + r) * DMODEL + kk + c8 * 8];
            *(int4*)&Bs[r][c8 * 8] = *(const int4*)&wo16[(size_t)(col0 + r) * DMODEL + kk + c8 * 8];
        }
        __syncthreads();

        f16x8 a[4], b[4];
        #pragma unroll
        for (int mi = 0; mi < 4; ++mi)
            a[mi] = *(const f16x8*)&As[wr * 64 + mi * 16 + (lane & 15)][(lane >> 4) * 8];
        #pragma unroll
        for (int ni = 0; ni < 4; ++ni)
            b[ni] = *(const f16x8*)&Bs[wc * 64 + ni * 16 + (lane & 15)][(lane >> 4) * 8];
        #pragma unroll
        for (int mi = 0; mi < 4; ++mi)
            #pragma unroll
            for (int ni = 0; ni < 4; ++ni)
                acc[mi][ni] = __builtin_amdgcn_mfma_f32_16x16x32_f16(a[mi], b[ni], acc[mi][ni], 0, 0, 0);
        __syncthreads();
    }

    #pragma unroll
    for (int mi = 0; mi < 4; ++mi)
        #pragma unroll
        for (int ni = 0; ni < 4; ++ni) {
            int col = col0 + wc * 64 + ni * 16 + (lane & 15);
            float bc = bo[col];
            #pragma unroll
            for (int r = 0; r < 4; ++r) {
                int row = row0 + wr * 64 + mi * 16 + (lane >> 4) * 4 + r;
                out[(size_t)row * DMODEL + col] = acc[mi][ni][r] + bc;
            }
        }
}

// ----------------------------------------------------------------- launch
extern "C" void kernel_launch(void* const* d_in, const int* in_sizes, int n_in,
                              void* d_out, int out_size, void* d_ws, size_t ws_size,
                              hipStream_t stream) {
    const float* q   = (const float*)d_in[0];
    const float* k   = (const float*)d_in[1];
    const float* v   = (const float*)d_in[2];
    const float* rel = (const float*)d_in[3];
    const float* wq  = (const float*)d_in[4];
    const float* bq  = (const float*)d_in[5];
    const float* wk  = (const float*)d_in[6];
    const float* bk  = (const float*)d_in[7];
    const float* wv  = (const float*)d_in[8];
    const float* bv  = (const float*)d_in[9];
    const float* wo  = (const float*)d_in[10];
    const float* bo  = (const float*)d_in[11];
    float* out = (float*)d_out;

    // workspace layout (halves): wo16 | rel16 | qh | kh | vt | att  = 36 MB total
    f16* ws    = (f16*)d_ws;
    f16* wo16  = ws;
    f16* rel16 = wo16 + (size_t)DMODEL * DMODEL;
    f16* qh16  = rel16 + (size_t)2 * MAXLEN * DKDIM;
    f16* kh16  = qh16 + (size_t)NTOK * DMODEL;
    f16* vt16  = kh16 + (size_t)NTOK * DMODEL;
    f16* att16 = vt16 + (size_t)NTOK * DMODEL;

    cvt_f32_f16<<<dim3(1024), 256, 0, stream>>>(wo, wo16, DMODEL * DMODEL / 4);
    cvt_f32_f16<<<dim3(256),  256, 0, stream>>>(rel, rel16, 2 * MAXLEN * DKDIM / 4);
    qkv_proj<<<dim3(8, 32, 3), 256, 0, stream>>>(q, k, v, wq, wk, wv, bq, bk, bv,
                                                 qh16, kh16, vt16);
    flash_attn<<<dim3(32, 32), 256, 0, stream>>>(qh16, kh16, vt16, rel16, att16);
    out_proj<<<dim3(8, 32), 256, 0, stream>>>(att16, wo16, bo, out);
}

// Round 2
// 394.437 us; speedup vs baseline: 1.1123x; 1.1123x over previous
//
#include <hip/hip_runtime.h>
#include <hip/hip_fp16.h>

// RelativeMultiHeadAttention on MI355X (gfx950), fp16 MFMA pipeline. Round 2.
//
// R2 changes (flash was LDS-pipe-bound: MfmaUtil 11%, ~875 LDS cyc/tile/wave):
//  - per-wave pos band 80 cols (was 128): pos MFMA 16->10, skew writes 32->20
//  - rolling rel-band buffer (mod 128): stage 64 new rows/tile (was 128)
//  - barriers 4->2 per tile (pos/P buffers are per-wave private; DS in-order)
//  - merged per-wave pos/P buffer: LDS 62.5->47 KB -> 3 blocks/CU
//  - s_setprio around MFMA clusters
//  - qkv/out_proj: BK=64
//
// MFMA 16x16x32_f16 fragment convention (m97-verified):
//   A/B operand: row/col = lane&15, k = 8*(lane>>4)+j (8 contiguous halves)
//   C/D:         col = lane&15,     row = 4*(lane>>4)+reg

typedef _Float16 f16;
typedef _Float16 f16x4 __attribute__((ext_vector_type(4)));
typedef _Float16 f16x8 __attribute__((ext_vector_type(8)));
typedef float    f32x4 __attribute__((ext_vector_type(4)));

#define NBATCH 2
#define NHEADS 16
#define DKDIM  64
#define SEQL   2048
#define DMODEL 1024
#define NTOK   4096
#define MAXLEN 2048

// ---------------------------------------------------------------- K0: convert
__global__ void cvt_f32_f16(const float* __restrict__ src, f16* __restrict__ dst, int n4) {
    int i = blockIdx.x * blockDim.x + threadIdx.x;
    if (i < n4) {
        float4 v = ((const float4*)src)[i];
        f16x4 h = { (f16)v.x, (f16)v.y, (f16)v.z, (f16)v.w };
        ((f16x4*)dst)[i] = h;
    }
}

// ------------------------------------------------------------ K1: QKV project
// C[n,o] = sum_i X[n,i]*W[o,i] + b[o]; 128x128 tile, 4 waves (2x2), BK=64.
__global__ __launch_bounds__(256) void qkv_proj(
    const float* __restrict__ qg, const float* __restrict__ kg, const float* __restrict__ vg,
    const float* __restrict__ wq, const float* __restrict__ wk, const float* __restrict__ wv,
    const float* __restrict__ bq, const float* __restrict__ bk, const float* __restrict__ bv,
    f16* __restrict__ qh, f16* __restrict__ kh, f16* __restrict__ vt)
{
    const int which = blockIdx.z;
    const float* X    = which == 0 ? qg : (which == 1 ? kg : vg);
    const float* W    = which == 0 ? wq : (which == 1 ? wk : wv);
    const float* bias = which == 0 ? bq : (which == 1 ? bk : bv);

    __shared__ f16 As[128][72];   // +8 pad: 144B stride (16B aligned)
    __shared__ f16 Bs[128][72];

    const int tid = threadIdx.x;
    const int lane = tid & 63;
    const int w = tid >> 6;
    const int wr = w >> 1, wc = w & 1;
    const int row0 = blockIdx.y * 128;
    const int col0 = blockIdx.x * 128;

    f32x4 acc[4][4] = {};

    for (int kk = 0; kk < DMODEL; kk += 64) {
        // stage + convert: 128x64 fp32 of X and W
        #pragma unroll
        for (int rep = 0; rep < 8; ++rep) {
            int idx = rep * 256 + tid;          // 0..2047
            int r = idx >> 4, seg = idx & 15;   // row, 4-float segment
            float4 va = *(const float4*)&X[(size_t)(row0 + r) * DMODEL + kk + seg * 4];
            f16x4 ha = { (f16)va.x, (f16)va.y, (f16)va.z, (f16)va.w };
            *(f16x4*)&As[r][seg * 4] = ha;
            float4 vb = *(const float4*)&W[(size_t)(col0 + r) * DMODEL + kk + seg * 4];
            f16x4 hb = { (f16)vb.x, (f16)vb.y, (f16)vb.z, (f16)vb.w };
            *(f16x4*)&Bs[r][seg * 4] = hb;
        }
        __syncthreads();

        f16x8 a[4][2], b[4][2];
        #pragma unroll
        for (int mi = 0; mi < 4; ++mi)
            #pragma unroll
            for (int ks = 0; ks < 2; ++ks)
                a[mi][ks] = *(const f16x8*)&As[wr * 64 + mi * 16 + (lane & 15)][ks * 32 + (lane >> 4) * 8];
        #pragma unroll
        for (int ni = 0; ni < 4; ++ni)
            #pragma unroll
            for (int ks = 0; ks < 2; ++ks)
                b[ni][ks] = *(const f16x8*)&Bs[wc * 64 + ni * 16 + (lane & 15)][ks * 32 + (lane >> 4) * 8];
        __builtin_amdgcn_s_setprio(1);
        #pragma unroll
        for (int mi = 0; mi < 4; ++mi)
            #pragma unroll
            for (int ni = 0; ni < 4; ++ni)
                #pragma unroll
                for (int ks = 0; ks < 2; ++ks)
                    acc[mi][ni] = __builtin_amdgcn_mfma_f32_16x16x32_f16(a[mi][ks], b[ni][ks], acc[mi][ni], 0, 0, 0);
        __builtin_amdgcn_s_setprio(0);
        __syncthreads();
    }

    // epilogue: +bias, scatter into head layouts
    #pragma unroll
    for (int mi = 0; mi < 4; ++mi) {
        #pragma unroll
        for (int ni = 0; ni < 4; ++ni) {
            int col = col0 + wc * 64 + ni * 16 + (lane & 15);
            int h = col >> 6, d = col & 63;
            float bc = bias[col];
            #pragma unroll
            for (int r = 0; r < 4; ++r) {
                int row = row0 + wr * 64 + mi * 16 + (lane >> 4) * 4 + r;
                int b_ = row >> 11, l = row & 2047;
                float val = acc[mi][ni][r] + bc;
                if (which == 0)
                    qh[((size_t)((b_ * 16 + h) * 2048 + l)) * 64 + d] = (f16)val;
                else if (which == 1)
                    kh[((size_t)((b_ * 16 + h) * 2048 + l)) * 64 + d] = (f16)val;
                else
                    vt[((size_t)((b_ * 16 + h) * 64 + d)) * 2048 + l] = (f16)val;
            }
        }
    }
}

// --------------------------------------------------------- K2: flash attention
// 4 waves; wave w owns Q rows [i0+16w, i0+16w+16). K/V tiles = 64 cols.
// pos via per-wave 80-col band GEMM + per-wave skew buffer (Qb).
__global__ __launch_bounds__(256, 3) void flash_attn(
    const f16* __restrict__ qh, const f16* __restrict__ kh, const f16* __restrict__ vt,
    const f16* __restrict__ rel, f16* __restrict__ att)
{
    const int tid = threadIdx.x, lane = tid & 63, w = tid >> 6;
    const int bh = blockIdx.y;          // b*16 + h
    const int b = bh >> 4, h = bh & 15;
    const int i0 = blockIdx.x * 64;

    __shared__ f16 Ks[64][72];          // K tile (prologue: Q stage)
    __shared__ f16 Vs[64][72];          // Vs[d][j]
    __shared__ f16 Rb[128][72];         // rolling rel band, slot = p & 127
    __shared__ f16 Qb[4][16][88];       // per-wave: pos band (80 cols), then P (64 cols)

    const size_t base_kq = (size_t)bh * SEQL * DKDIM;
    const int pb0 = MAXLEN - i0 - 63;   // abs rel row of window start at j0=0 (>=1)

    // ---- prologue: stage Q into Ks; stage Rb rows [pb0, pb0+64)
    #pragma unroll
    for (int rep = 0; rep < 2; ++rep) {
        int idx = rep * 256 + tid;       // 0..511
        int r = idx >> 3, seg = idx & 7;
        *(int4*)&Ks[r][seg * 8] = *(const int4*)&qh[base_kq + (size_t)(i0 + r) * 64 + seg * 8];
        int p = pb0 + r;
        *(int4*)&Rb[p & 127][seg * 8] = *(const int4*)&rel[(size_t)p * 64 + seg * 8];
    }
    __syncthreads();
    f16x8 aq[2];
    aq[0] = *(const f16x8*)&Ks[w * 16 + (lane & 15)][(lane >> 4) * 8];
    aq[1] = *(const f16x8*)&Ks[w * 16 + (lane & 15)][32 + (lane >> 4) * 8];
    __syncthreads();   // aq read before Ks is overwritten by K staging

    float mrun[4], lrun[4];
    f32x4 oacc[4] = {};
    #pragma unroll
    for (int r = 0; r < 4; ++r) { mrun[r] = -1e30f; lrun[r] = 0.f; }

    const int p0w_off = 48 - w * 16;    // per-wave band offset within window

    for (int j0 = 0; j0 < SEQL; j0 += 64) {
        // ---- stage K tile, V tile, 64 new rel rows (rolling)
        #pragma unroll
        for (int rep = 0; rep < 2; ++rep) {
            int idx = rep * 256 + tid;
            int r = idx >> 3, seg = idx & 7;
            *(int4*)&Ks[r][seg * 8] = *(const int4*)&kh[base_kq + (size_t)(j0 + r) * 64 + seg * 8];
            *(int4*)&Vs[r][seg * 8] = *(const int4*)&vt[base_kq + (size_t)r * 2048 + j0 + seg * 8];
            int p = pb0 + j0 + 64 + r;
            int slot = p & 127;                 // slot from UNclamped p
            if (p > 4095) p = 4095;             // clamped row is never read
            *(int4*)&Rb[slot][seg * 8] = *(const int4*)&rel[(size_t)p * 64 + seg * 8];
        }
        __syncthreads();

        // ---- content scores S (16 own rows x 64 cols) + per-wave pos band (80 cols)
        const int p0w = pb0 + j0 + p0w_off;
        f32x4 sacc[4] = {};
        f32x4 qracc[5] = {};
        __builtin_amdgcn_s_setprio(1);
        #pragma unroll
        for (int nf = 0; nf < 4; ++nf)
            #pragma unroll
            for (int ks = 0; ks < 2; ++ks) {
                f16x8 bk = *(const f16x8*)&Ks[nf * 16 + (lane & 15)][ks * 32 + (lane >> 4) * 8];
                sacc[nf] = __builtin_amdgcn_mfma_f32_16x16x32_f16(aq[ks], bk, sacc[nf], 0, 0, 0);
            }
        #pragma unroll
        for (int pf = 0; pf < 5; ++pf)
            #pragma unroll
            for (int ks = 0; ks < 2; ++ks) {
                f16x8 br = *(const f16x8*)&Rb[(p0w + pf * 16 + (lane & 15)) & 127][ks * 32 + (lane >> 4) * 8];
                qracc[pf] = __builtin_amdgcn_mfma_f32_16x16x32_f16(aq[ks], br, qracc[pf], 0, 0, 0);
            }
        __builtin_amdgcn_s_setprio(0);

        // ---- pos band -> per-wave LDS (plain layout [row][band col])
        #pragma unroll
        for (int pf = 0; pf < 5; ++pf)
            #pragma unroll
            for (int r = 0; r < 4; ++r)
                Qb[w][(lane >> 4) * 4 + r][pf * 16 + (lane & 15)] = (f16)qracc[pf][r];

        // ---- skew gather + scale, then online softmax (wave-private, no barrier)
        float p_[4][4];
        #pragma unroll
        for (int nf = 0; nf < 4; ++nf)
            #pragma unroll
            for (int r = 0; r < 4; ++r) {
                int gi = (lane >> 4) * 4 + r;            // within-wave row
                int c = nf * 16 + (lane & 15) - gi + 15; // band col, 0..78
                p_[nf][r] = (sacc[nf][r] + (float)Qb[w][gi][c]) * 0.125f;
            }
        float scale[4];
        #pragma unroll
        for (int r = 0; r < 4; ++r) {
            float mx = fmaxf(fmaxf(p_[0][r], p_[1][r]), fmaxf(p_[2][r], p_[3][r]));
            #pragma unroll
            for (int m = 8; m >= 1; m >>= 1) mx = fmaxf(mx, __shfl_xor(mx, m, 64));
            float mnew = fmaxf(mrun[r], mx);
            scale[r] = __expf(mrun[r] - mnew);
            float sm = 0.f;
            #pragma unroll
            for (int nf = 0; nf < 4; ++nf) { p_[nf][r] = __expf(p_[nf][r] - mnew); sm += p_[nf][r]; }
            #pragma unroll
            for (int m = 8; m >= 1; m >>= 1) sm += __shfl_xor(sm, m, 64);
            lrun[r] = lrun[r] * scale[r] + sm;
            mrun[r] = mnew;
        }
        #pragma unroll
        for (int df = 0; df < 4; ++df)
            #pragma unroll
            for (int r = 0; r < 4; ++r) oacc[df][r] *= scale[r];

        // ---- P -> per-wave LDS (A-operand relayout; overwrites band cols 0..63)
        #pragma unroll
        for (int nf = 0; nf < 4; ++nf)
            #pragma unroll
            for (int r = 0; r < 4; ++r)
                Qb[w][(lane >> 4) * 4 + r][nf * 16 + (lane & 15)] = (f16)p_[nf][r];
        f16x8 pa[2];
        pa[0] = *(const f16x8*)&Qb[w][lane & 15][(lane >> 4) * 8];
        pa[1] = *(const f16x8*)&Qb[w][lane & 15][32 + (lane >> 4) * 8];
        __builtin_amdgcn_s_setprio(1);
        #pragma unroll
        for (int df = 0; df < 4; ++df)
            #pragma unroll
            for (int ks = 0; ks < 2; ++ks) {
                f16x8 bv = *(const f16x8*)&Vs[df * 16 + (lane & 15)][ks * 32 + (lane >> 4) * 8];
                oacc[df] = __builtin_amdgcn_mfma_f32_16x16x32_f16(pa[ks], bv, oacc[df], 0, 0, 0);
            }
        __builtin_amdgcn_s_setprio(0);
        __syncthreads();   // WAR: next staging overwrites Ks/Vs/Rb
    }

    // ---- epilogue: normalize, write att[b*L + i][h*64 + d]
    #pragma unroll
    for (int df = 0; df < 4; ++df) {
        int d = df * 16 + (lane & 15);
        #pragma unroll
        for (int r = 0; r < 4; ++r) {
            int i = i0 + w * 16 + (lane >> 4) * 4 + r;
            float val = oacc[df][r] / lrun[r];
            att[((size_t)(b * 2048 + i)) * DMODEL + h * 64 + d] = (f16)val;
        }
    }
}

// ------------------------------------------------------------- K3: out project
__global__ __launch_bounds__(256) void out_proj(
    const f16* __restrict__ att, const f16* __restrict__ wo16, const float* __restrict__ bo,
    float* __restrict__ out)
{
    __shared__ f16 As[128][72];
    __shared__ f16 Bs[128][72];
    const int tid = threadIdx.x, lane = tid & 63, w = tid >> 6;
    const int wr = w >> 1, wc = w & 1;
    const int row0 = blockIdx.y * 128, col0 = blockIdx.x * 128;

    f32x4 acc[4][4] = {};

    for (int kk = 0; kk < DMODEL; kk += 64) {
        #pragma unroll
        for (int rep = 0; rep < 4; ++rep) {
            int idx = rep * 256 + tid;       // 0..1023
            int r = idx >> 3, seg = idx & 7;
            *(int4*)&As[r][seg * 8] = *(const int4*)&att[(size_t)(row0 + r) * DMODEL + kk + seg * 8];
            *(int4*)&Bs[r][seg * 8] = *(const int4*)&wo16[(size_t)(col0 + r) * DMODEL + kk + seg * 8];
        }
        __syncthreads();

        f16x8 a[4][2], b[4][2];
        #pragma unroll
        for (int mi = 0; mi < 4; ++mi)
            #pragma unroll
            for (int ks = 0; ks < 2; ++ks)
                a[mi][ks] = *(const f16x8*)&As[wr * 64 + mi * 16 + (lane & 15)][ks * 32 + (lane >> 4) * 8];
        #pragma unroll
        for (int ni = 0; ni < 4; ++ni)
            #pragma unroll
            for (int ks = 0; ks < 2; ++ks)
                b[ni][ks] = *(const f16x8*)&Bs[wc * 64 + ni * 16 + (lane & 15)][ks * 32 + (lane >> 4) * 8];
        __builtin_amdgcn_s_setprio(1);
        #pragma unroll
        for (int mi = 0; mi < 4; ++mi)
            #pragma unroll
            for (int ni = 0; ni < 4; ++ni)
                #pragma unroll
                for (int ks = 0; ks < 2; ++ks)
                    acc[mi][ni] = __builtin_amdgcn_mfma_f32_16x16x32_f16(a[mi][ks], b[ni][ks], acc[mi][ni], 0, 0, 0);
        __builtin_amdgcn_s_setprio(0);
        __syncthreads();
    }

    #pragma unroll
    for (int mi = 0; mi < 4; ++mi)
        #pragma unroll
        for (int ni = 0; ni < 4; ++ni) {
            int col = col0 + wc * 64 + ni * 16 + (lane & 15);
            float bc = bo[col];
            #pragma unroll
            for (int r = 0; r < 4; ++r) {
                int row = row0 + wr * 64 + mi * 16 + (lane >> 4) * 4 + r;
                out[(size_t)row * DMODEL + col] = acc[mi][ni][r] + bc;
            }
        }
}

// ----------------------------------------------------------------- launch
extern "C" void kernel_launch(void* const* d_in, const int* in_sizes, int n_in,
                              void* d_out, int out_size, void* d_ws, size_t ws_size,
                              hipStream_t stream) {
    const float* q   = (const float*)d_in[0];
    const float* k   = (const float*)d_in[1];
    const float* v   = (const float*)d_in[2];
    const float* rel = (const float*)d_in[3];
    const float* wq  = (const float*)d_in[4];
    const float* bq  = (const float*)d_in[5];
    const float* wk  = (const float*)d_in[6];
    const float* bk  = (const float*)d_in[7];
    const float* wv  = (const float*)d_in[8];
    const float* bv  = (const float*)d_in[9];
    const float* wo  = (const float*)d_in[10];
    const float* bo  = (const float*)d_in[11];
    float* out = (float*)d_out;

    // workspace layout (halves): wo16 | rel16 | qh | kh | vt | att  = 36 MB total
    f16* ws    = (f16*)d_ws;
    f16* wo16  = ws;
    f16* rel16 = wo16 + (size_t)DMODEL * DMODEL;
    f16* qh16  = rel16 + (size_t)2 * MAXLEN * DKDIM;
    f16* kh16  = qh16 + (size_t)NTOK * DMODEL;
    f16* vt16  = kh16 + (size_t)NTOK * DMODEL;
    f16* att16 = vt16 + (size_t)NTOK * DMODEL;

    cvt_f32_f16<<<dim3(1024), 256, 0, stream>>>(wo, wo16, DMODEL * DMODEL / 4);
    cvt_f32_f16<<<dim3(256),  256, 0, stream>>>(rel, rel16, 2 * MAXLEN * DKDIM / 4);
    qkv_proj<<<dim3(8, 32, 3), 256, 0, stream>>>(q, k, v, wq, wk, wv, bq, bk, bv,
                                                 qh16, kh16, vt16);
    flash_attn<<<dim3(32, 32), 256, 0, stream>>>(qh16, kh16, vt16, rel16, att16);
    out_proj<<<dim3(8, 32), 256, 0, stream>>>(att16, wo16, bo, out);
}